// Round 20
// baseline (174.113 us; speedup 1.0000x reference)
//
#include <hip/hip_runtime.h>
#include <cstdint>
#include <cstddef>

#define NB  8
#define NC  128
#define NHW 36864

// workspace layout (float offsets)
#define GOFF  0         // 131072
#define SOFF  131072    // 1024
#define TOFF  132096    // 1024
#define ROFF  133120    // 131072
#define CVOFF 264192    // 1024
#define MBOFF 265216    // 65536 floats = 131072 shorts (bf16 I + gamma*M fragments)

typedef __attribute__((ext_vector_type(8))) short short8;
typedef __attribute__((ext_vector_type(4))) float f32x4;

static __device__ __forceinline__ f32x4 zero4(){ f32x4 v = {0.f,0.f,0.f,0.f}; return v; }

// float -> bf16 bits via native __bf16 (compiler emits v_cvt_pk_bf16_f32 pairs)
static __device__ __forceinline__ short bfbits(float f){
    union { __bf16 b; short s; } u; u.b = (__bf16)f; return u.s;
}
// hi/lo split: h = bf16(f), l = bf16(f - float(h))
static __device__ __forceinline__ void cv2(float f, short& hb, short& lb){
    union { __bf16 b; short s; } u;
    u.b = (__bf16)f; hb = u.s;
    float hf = (float)u.b;
    u.b = (__bf16)(f - hf); lb = u.s;
}
// two f32x4 (8 consecutive cols) -> hi/lo short8 fragments; returns sum
static __device__ __forceinline__ float cv8(f32x4 v0, f32x4 v1, short8& h, short8& l){
    float ss = 0.f;
#pragma unroll
    for (int j=0;j<4;j++){
        short hb, lb;
        cv2(v0[j], hb, lb); h[j]   = hb; l[j]   = lb;
        cv2(v1[j], hb, lb); h[4+j] = hb; l[4+j] = lb;
        ss += v0[j] + v1[j];
    }
    return ss;
}

// ---- K0: zero G and svec (atomic accumulation targets) ----
__global__ __launch_bounds__(256) void k_zero(float* __restrict__ p){
    const int i = (blockIdx.x*256 + threadIdx.x)*4;
    *(f32x4*)(p + i) = zero4();
}

// ======================= K1: Gram G = sum_n x x^T ==========================
// Round-20 change (k_gram only): chunks 32 -> 64 (512 blocks = 2 blocks/CU,
// 64+64 KB LDS) so two INDEPENDENT barrier domains share each CU — while one
// block drains its prefetch loads, the other computes. GNT 36 -> 18; phase-B
// pair-load guarded (4jp+6 < GNT) to avoid OOB at the last chunk; tail is
// just the final two staged tiles. Structure otherwise round-18/19 verbatim
// (4 LDS buffers, 2 tiles/barrier, depth-2 reg prefetch, conflict-free XOR
// swizzle, 2x4 wave mapping). Numerics bit-identical (absmax must stay 0.03125).
#define GNT 18          // 18 tiles * 32 n = 576 n per chunk
#define GTS 4096        // shorts per (buf,half): 128*32

__global__ __launch_bounds__(512) void k_gram(const float* __restrict__ x,
                                              float* __restrict__ G,
                                              float* __restrict__ svec){
    __shared__ short Ls[4][2][GTS];    // [buf][hi/lo][row*32 + swizzled col] : 64 KB
    const int b     = blockIdx.y;
    const int chunk = blockIdx.x;      // 64 chunks * 576 n
    const int tid   = threadIdx.x;
    const int wid   = tid >> 6, lane = tid & 63;
    const int l16   = lane & 15, lgi = lane >> 4;
    const int rgp   = wid >> 1;          // rowgroup pair (rows rgp*32..rgp*32+31)
    const int chh   = wid & 1;           // colgroup half (cg = chh*4..chh*4+3)
    const int sr    = tid >> 2;          // staging row (0..127)
    const int sc8   = (tid & 3) * 8;     // staging col-octet (0,8,16,24)
    const int swzW  = ((sr >> 1) & 3) << 3;
    const int wIdx  = sr*32 + (sc8 ^ swzW);          // staging write index

    const int swzR  = ((l16 >> 1) & 3) << 3;         // read swizzle (row = *16 + l16)
    const int cR    = (lgi*8) ^ swzR;                // swizzled col for b128 reads
    const int raOff0 = (rgp*32      + l16)*32 + cR;  // A-frag idx, rowgroup rgp*2
    const int raOff1 = (rgp*32 + 16 + l16)*32 + cR;  // A-frag idx, rowgroup rgp*2+1

    const float* xs = x + (size_t)b*NC*NHW + (size_t)sr*NHW + chunk*576 + sc8;

    float srow = 0.f;
    f32x4 acc[2][4];
#pragma unroll
    for (int p=0;p<2;p++)
#pragma unroll
      for (int g=0;g<4;g++) acc[p][g] = zero4();

#define GR_STAGE(BUF, V0, V1)  { short8 h0,l0; srow += cv8(V0,V1,h0,l0); \
        *(short8*)&Ls[BUF][0][wIdx] = h0; *(short8*)&Ls[BUF][1][wIdx] = l0; }

#define GR_COMPUTE(BUF) { \
        const short* Lh = &Ls[BUF][0][0]; \
        const short* Ll = &Ls[BUF][1][0]; \
        short8 hA0 = *(const short8*)(Lh + raOff0); \
        short8 lA0 = *(const short8*)(Ll + raOff0); \
        short8 hA1 = *(const short8*)(Lh + raOff1); \
        short8 lA1 = *(const short8*)(Ll + raOff1); \
        _Pragma("unroll") \
        for (int g=0; g<4; g++){ \
            const int rb = ((chh*4 + g)*16 + l16)*32 + cR; \
            short8 hg  = *(const short8*)(Lh + rb); \
            short8 lg2 = *(const short8*)(Ll + rb); \
            acc[0][g] = __builtin_amdgcn_mfma_f32_16x16x32_bf16(hA0, hg,  acc[0][g], 0,0,0); \
            acc[0][g] = __builtin_amdgcn_mfma_f32_16x16x32_bf16(hA0, lg2, acc[0][g], 0,0,0); \
            acc[0][g] = __builtin_amdgcn_mfma_f32_16x16x32_bf16(lA0, hg,  acc[0][g], 0,0,0); \
            acc[1][g] = __builtin_amdgcn_mfma_f32_16x16x32_bf16(hA1, hg,  acc[1][g], 0,0,0); \
            acc[1][g] = __builtin_amdgcn_mfma_f32_16x16x32_bf16(hA1, lg2, acc[1][g], 0,0,0); \
            acc[1][g] = __builtin_amdgcn_mfma_f32_16x16x32_bf16(lA1, hg,  acc[1][g], 0,0,0); \
        } }

    // prologue: tiles 0,1 staged directly; tiles 2,3 loaded into pair-0 regs
    {
        f32x4 v0 = *(const f32x4*)(xs);
        f32x4 v1 = *(const f32x4*)(xs+4);
        GR_STAGE(0, v0, v1);
        f32x4 u0 = *(const f32x4*)(xs+32);
        f32x4 u1 = *(const f32x4*)(xs+36);
        GR_STAGE(1, u0, u1);
    }
    f32x4 a0A = *(const f32x4*)(xs + 2*32);     // tile 2
    f32x4 a0B = *(const f32x4*)(xs + 2*32 + 4);
    f32x4 b0A = *(const f32x4*)(xs + 3*32);     // tile 3
    f32x4 b0B = *(const f32x4*)(xs + 3*32 + 4);
    f32x4 a1A, a1B, b1A, b1B;
    __syncthreads();

    for (int jp=0; jp<GNT/4; ++jp){   // GNT=18 -> jp=0..3 covers tiles 0..15
        // phase A: compute tiles 4jp,4jp+1 (buf0,1); stage 4jp+2,4jp+3 from
        // pair-0 into buf2,3; load 4jp+4,4jp+5 into pair-1 (max 16,17 ok).
        {
            const float* p = xs + (size_t)(4*jp+4)*32;
            a1A = *(const f32x4*)(p);       a1B = *(const f32x4*)(p+4);
            b1A = *(const f32x4*)(p+32);    b1B = *(const f32x4*)(p+36);
        }
        __builtin_amdgcn_sched_barrier(0);
        GR_COMPUTE(0); GR_COMPUTE(1);
        GR_STAGE(2, a0A, a0B); GR_STAGE(3, b0A, b0B);
        __syncthreads();
        // phase B: compute tiles 4jp+2,4jp+3 (buf2,3); stage 4jp+4,4jp+5 from
        // pair-1 into buf0,1; load 4jp+6,4jp+7 into pair-0 (GUARDED: OOB at end).
        if (4*jp+6 < GNT){
            const float* p = xs + (size_t)(4*jp+6)*32;
            a0A = *(const f32x4*)(p);       a0B = *(const f32x4*)(p+4);
            b0A = *(const f32x4*)(p+32);    b0B = *(const f32x4*)(p+36);
        }
        __builtin_amdgcn_sched_barrier(0);
        GR_COMPUTE(2); GR_COMPUTE(3);
        GR_STAGE(0, a1A, a1B); GR_STAGE(1, b1A, b1B);
        __syncthreads();
    }
    // after loop (GNT=18): tiles 0..15 computed; tiles 16,17 staged in buf0,1.
    GR_COMPUTE(0); GR_COMPUTE(1);              // tiles 16,17

#undef GR_STAGE
#undef GR_COMPUTE

    // C/D layout (pass-verified): col = lane&15, row = (lane>>4)*4 + reg
    float* Gb = G + (size_t)b*NC*NC;
#pragma unroll
    for (int p=0;p<2;p++){
        const int rg = rgp*2 + p;
#pragma unroll
        for (int g=0;g<4;g++){
            const int gg = chh*4 + g;
#pragma unroll
            for (int r=0;r<4;r++){
                atomicAdd(&Gb[(size_t)(rg*16 + lgi*4 + r)*NC + gg*16 + l16], acc[p][g][r]);
            }
        }
    }
    srow += __shfl_xor(srow, 1);
    srow += __shfl_xor(srow, 2);
    if ((tid & 3) == 0) atomicAdd(&svec[b*NC + sr], srow);
}

// ---- K2: energy = Wq G Wk^T + rank-1 terms; softmax -> A (LDS); t = A bv; R = A Wv ----
// (round-19 verbatim, PASSING)
__global__ __launch_bounds__(256) void k_energyav(const float* __restrict__ G,
        const float* __restrict__ svec,
        const float* __restrict__ Wq, const float* __restrict__ bq,
        const float* __restrict__ Wk, const float* __restrict__ bk,
        const float* __restrict__ bv, const float* __restrict__ Wv,
        float* __restrict__ R, float* __restrict__ tvec){
    const int b  = blockIdx.y;
    const int d0 = blockIdx.x * 16;
    const int tid = threadIdx.x;
    const int d  = tid & 15;
    const int ec = tid >> 4;

    __shared__ float Ps[16][128];
    __shared__ float Es[16][128];
    __shared__ float red[16][16];
    __shared__ float rowmax[16];
    __shared__ float rowsum[16];
    __shared__ float qs[16];

    const float* Wqrow = Wq + (size_t)(d0 + d)*NC;
    const float* sb = svec + b*NC;
#pragma unroll
    for (int i=0;i<8;i++){
        const int c = ec*8 + i;
        const float* Grow = G + ((size_t)b*NC + c)*NC;
        float a = 0.f;
        for (int c4=0;c4<32;c4++){
            f32x4 g4 = *(const f32x4*)(Grow + c4*4);
            f32x4 w4 = *(const f32x4*)(Wqrow + c4*4);
            a += g4[0]*w4[0] + g4[1]*w4[1] + g4[2]*w4[2] + g4[3]*w4[3];
        }
        Ps[d][c] = a;
    }
    if (ec == 0){
        float a = 0.f;
        for (int c4=0;c4<32;c4++){
            f32x4 w4 = *(const f32x4*)(Wqrow + c4*4);
            f32x4 s4 = *(const f32x4*)(sb + c4*4);
            a += w4[0]*s4[0] + w4[1]*s4[1] + w4[2]*s4[2] + w4[3]*s4[3];
        }
        qs[d] = a;
    }
    __syncthreads();
    const float bqd = bq[d0+d];
#pragma unroll
    for (int i=0;i<8;i++){
        const int e = ec*8 + i;
        const float* Wkrow = Wk + (size_t)e*NC;
        float ea = 0.f, ks = 0.f;
        for (int c4=0;c4<32;c4++){
            f32x4 w4 = *(const f32x4*)(Wkrow + c4*4);
            f32x4 p4 = *(const f32x4*)(&Ps[d][c4*4]);
            f32x4 s4 = *(const f32x4*)(sb + c4*4);
            ea += w4[0]*p4[0]+w4[1]*p4[1]+w4[2]*p4[2]+w4[3]*p4[3];
            ks += w4[0]*s4[0]+w4[1]*s4[1]+w4[2]*s4[2]+w4[3]*s4[3];
        }
        const float bke = bk[e];
        Es[d][e] = ea + bke*qs[d] + bqd*ks + (float)NHW*bqd*bke;
    }
    float m8 = -3.4e38f;
#pragma unroll
    for (int i=0;i<8;i++) m8 = fmaxf(m8, Es[d][ec*8+i]);
    red[d][ec] = m8;
    __syncthreads();
    if (tid < 16){
        float m = red[tid][0];
        for (int j=1;j<16;j++) m = fmaxf(m, red[tid][j]);
        rowmax[tid] = m;
    }
    __syncthreads();
    const float rm = rowmax[d];
    float s8 = 0.f;
#pragma unroll
    for (int i=0;i<8;i++){
        float ex = expf(Es[d][ec*8+i] - rm);
        Es[d][ec*8+i] = ex;
        s8 += ex;
    }
    red[d][ec] = s8;
    __syncthreads();
    if (tid < 16){
        float sm = 0.f;
        for (int j=0;j<16;j++) sm += red[tid][j];
        rowsum[tid] = sm;
    }
    __syncthreads();
    const float inv = 1.f / rowsum[d];
    float ta = 0.f;
#pragma unroll
    for (int i=0;i<8;i++){
        const int e = ec*8 + i;
        float av = Es[d][e] * inv;
        Es[d][e] = av;
        ta += av * bv[e];
    }
    red[d][ec] = ta;
    __syncthreads();
    if (tid < 16){
        float sm = 0.f;
        for (int j=0;j<16;j++) sm += red[tid][j];
        tvec[b*NC + d0 + tid] = sm;
    }
    const int c0 = ec*8;
    float racc[8];
#pragma unroll
    for (int i=0;i<8;i++) racc[i]=0.f;
    for (int e=0;e<NC;e++){
        const float av = Es[d][e];
        const float* wv = Wv + (size_t)e*NC + c0;
        f32x4 w0 = *(const f32x4*)wv;
        f32x4 w1 = *(const f32x4*)(wv+4);
        racc[0]+=av*w0[0]; racc[1]+=av*w0[1]; racc[2]+=av*w0[2]; racc[3]+=av*w0[3];
        racc[4]+=av*w1[0]; racc[5]+=av*w1[1]; racc[6]+=av*w1[2]; racc[7]+=av*w1[3];
    }
    float* Rrow = R + ((size_t)b*NC + d0 + d)*NC + c0;
#pragma unroll
    for (int i=0;i<8;i++) Rrow[i] = racc[i];
}

// ---- K3: Mb = bf16(I + gamma*Wo*R) single buffer; cvg = gamma*(Wo t + bo) ----
// (round-19 verbatim, PASSING)
__global__ __launch_bounds__(256) void k_om(const float* __restrict__ R,
        const float* __restrict__ Wo, const float* __restrict__ bo,
        const float* __restrict__ tvec, const float* __restrict__ gamma,
        short* __restrict__ Mb_, float* __restrict__ cvg){
    const int b = blockIdx.y, o0 = blockIdx.x*16;
    const int tid = threadIdx.x, o = tid&15, cc = tid>>4;
    const int c0 = cc*8;                      // cin octet base
    const float* Worow = Wo + (size_t)(o0+o)*NC;
    const float* tb = tvec + b*NC;
    float a[8];
#pragma unroll
    for (int i=0;i<8;i++) a[i]=0.f;
    float cv = 0.f;
    for (int dd=0; dd<NC; dd++){
        const float wv = Worow[dd];
        const float* r = R + ((size_t)b*NC + dd)*NC + c0;
        f32x4 r0 = *(const f32x4*)r;
        f32x4 r1 = *(const f32x4*)(r+4);
        a[0]+=wv*r0[0]; a[1]+=wv*r0[1]; a[2]+=wv*r0[2]; a[3]+=wv*r0[3];
        a[4]+=wv*r1[0]; a[5]+=wv*r1[1]; a[6]+=wv*r1[2]; a[7]+=wv*r1[3];
        cv += wv*tb[dd];
    }
    const float gm = gamma[0];
    const int c   = o0 + o;
    const int cg  = c >> 4;
    const int kst = cc >> 2, lgv = cc & 3;
    const size_t idx = ((((size_t)b*8 + cg)*4 + kst)*64 + (lgv*16 + (c & 15)))*8;
    short8 hh;
#pragma unroll
    for (int i=0;i<8;i++){
        float val = gm*a[i] + ((c0 + i) == c ? 1.f : 0.f);   // M' = I + gm*M
        hh[i] = bfbits(val);
    }
    *(short8*)(Mb_ + idx) = hh;
    if (cc == 0) cvg[b*NC + c] = gm*(cv + bo[c]);
}

// ---- K4: out = M' x + cvg  (A = x from swizzled Xt; B = Mb single bf16) ----
// (round-19 verbatim, PASSING)
__global__ __launch_bounds__(256, 4) void k_final(const float* __restrict__ x,
        const short* __restrict__ Mb_, const float* __restrict__ cvg,
        float* __restrict__ out){
    __shared__ short Xt[NC*128];   // 32 KB: row n (local), 16 slots of 8 shorts
    const int b   = blockIdx.y;
    const int n0  = blockIdx.x * 128;
    const int tid = threadIdx.x;
    const int wid = tid >> 6, lane = tid & 63;
    const int l16 = lane & 15, lgi = lane >> 4;

    // ---- stage: thread (nr = tid&31, mb8 = tid>>5), 2 reps
    const int nr = tid & 31, mb8 = tid >> 5;
    const float* xs = x + (size_t)b*NC*NHW + n0 + nr*4;
#pragma unroll
    for (int rep=0; rep<2; rep++){
        const int m0 = rep*64 + mb8*8;
        const float* xm = xs + (size_t)m0*NHW;
        f32x4 v0 = *(const f32x4*)(xm);
        f32x4 v1 = *(const f32x4*)(xm + (size_t)1*NHW);
        f32x4 v2 = *(const f32x4*)(xm + (size_t)2*NHW);
        f32x4 v3 = *(const f32x4*)(xm + (size_t)3*NHW);
        f32x4 v4 = *(const f32x4*)(xm + (size_t)4*NHW);
        f32x4 v5 = *(const f32x4*)(xm + (size_t)5*NHW);
        f32x4 v6 = *(const f32x4*)(xm + (size_t)6*NHW);
        f32x4 v7 = *(const f32x4*)(xm + (size_t)7*NHW);
#pragma unroll
        for (int r=0;r<4;r++){
            short8 w;
            w[0]=bfbits(v0[r]); w[1]=bfbits(v1[r]); w[2]=bfbits(v2[r]); w[3]=bfbits(v3[r]);
            w[4]=bfbits(v4[r]); w[5]=bfbits(v5[r]); w[6]=bfbits(v6[r]); w[7]=bfbits(v7[r]);
            const int n = nr*4 + r;
            const int slot = (rep*8 + mb8) ^ ((n>>2)&15) ^ ((n&3)<<2);
            *(short8*)(&Xt[n*128 + slot*8]) = w;
        }
    }
    __syncthreads();

    f32x4 acc[2][8];   // [n 16-block t][cg]
#pragma unroll
    for (int t=0;t<2;t++)
#pragma unroll
      for (int g=0;g<8;g++) acc[t][g]=zero4();

    const short* Mb = Mb_ + (size_t)b*16384;

#pragma unroll
    for (int ks=0; ks<4; ks++){
        const int nA0 = wid*32 + l16;
        const int nA1 = nA0 + 16;
        const int sl  = ks*4 + lgi;
        const int s0  = sl ^ ((nA0>>2)&15) ^ ((nA0&3)<<2);
        const int s1  = sl ^ ((nA1>>2)&15) ^ ((nA1&3)<<2);
        short8 a0 = *(const short8*)(&Xt[nA0*128 + s0*8]);
        short8 a1 = *(const short8*)(&Xt[nA1*128 + s1*8]);
#pragma unroll
        for (int cg=0; cg<8; cg++){
            short8 bh = *(const short8*)(Mb + (((size_t)cg*4 + ks)*64 + lane)*8);
            acc[0][cg] = __builtin_amdgcn_mfma_f32_16x16x32_bf16(a0, bh, acc[0][cg], 0,0,0);
            acc[1][cg] = __builtin_amdgcn_mfma_f32_16x16x32_bf16(a1, bh, acc[1][cg], 0,0,0);
        }
    }

    // C/D: row(i)=n-offset=(lane>>4)*4+r, col(j)=c=cg*16+(lane&15)
    const float* cb = cvg + b*NC;
#pragma unroll
    for (int cg=0;cg<8;cg++){
        const int c = cg*16 + l16;
        const float ccv = cb[c];
        float* orow = &out[((size_t)b*NC + c)*NHW + n0 + wid*32 + lgi*4];
#pragma unroll
        for (int t=0;t<2;t++){
            f32x4 o = acc[t][cg];
            o[0]+=ccv; o[1]+=ccv; o[2]+=ccv; o[3]+=ccv;
            *(f32x4*)(orow + t*16) = o;
        }
    }
}

extern "C" void kernel_launch(void* const* d_in, const int* in_sizes, int n_in,
                              void* d_out, int out_size, void* d_ws, size_t ws_size,
                              hipStream_t stream){
    const float* x     = (const float*)d_in[0];
    const float* Wq    = (const float*)d_in[1];
    const float* bq    = (const float*)d_in[2];
    const float* Wk    = (const float*)d_in[3];
    const float* bk    = (const float*)d_in[4];
    const float* Wv    = (const float*)d_in[5];
    const float* bv    = (const float*)d_in[6];
    const float* Wo    = (const float*)d_in[7];
    const float* bo    = (const float*)d_in[8];
    const float* gamma = (const float*)d_in[9];
    float* out = (float*)d_out;

    float* w  = (float*)d_ws;
    float* G  = w + GOFF;
    float* S  = w + SOFF;
    float* T  = w + TOFF;
    float* R  = w + ROFF;
    float* CV = w + CVOFF;
    short* Mb = (short*)(w + MBOFF);

    // zero atomic-accumulation targets (G: 131072 + svec: 1024 floats)
    k_zero    <<<dim3(129),     256, 0, stream>>>(G);

    k_gram    <<<dim3(64,  NB), 512, 0, stream>>>(x, G, S);
    k_energyav<<<dim3(8,   NB), 256, 0, stream>>>(G, S, Wq, bq, Wk, bk, bv, Wv, R, T);
    k_om      <<<dim3(8,   NB), 256, 0, stream>>>(R, Wo, bo, T, gamma, Mb, CV);
    k_final   <<<dim3(288, NB), 256, 0, stream>>>(x, Mb, CV, out);
}

// Round 21
// 168.368 us; speedup vs baseline: 1.0341x; 1.0341x over previous
//
#include <hip/hip_runtime.h>
#include <cstdint>
#include <cstddef>

#define NB  8
#define NC  128
#define NHW 36864

// workspace layout (float offsets)
#define GOFF  0         // 131072
#define SOFF  131072    // 1024
#define TOFF  132096    // 1024
#define ROFF  133120    // 131072
#define CVOFF 264192    // 1024
#define MBOFF 265216    // 65536 floats = 131072 shorts (bf16 I + gamma*M fragments)

typedef __attribute__((ext_vector_type(8))) short short8;
typedef __attribute__((ext_vector_type(4))) float f32x4;

static __device__ __forceinline__ f32x4 zero4(){ f32x4 v = {0.f,0.f,0.f,0.f}; return v; }

// float -> bf16 bits via native __bf16 (compiler emits v_cvt_pk_bf16_f32 pairs)
static __device__ __forceinline__ short bfbits(float f){
    union { __bf16 b; short s; } u; u.b = (__bf16)f; return u.s;
}
// hi/lo split: h = bf16(f), l = bf16(f - float(h))
static __device__ __forceinline__ void cv2(float f, short& hb, short& lb){
    union { __bf16 b; short s; } u;
    u.b = (__bf16)f; hb = u.s;
    float hf = (float)u.b;
    u.b = (__bf16)(f - hf); lb = u.s;
}
// two f32x4 (8 consecutive cols) -> hi/lo short8 fragments; returns sum
static __device__ __forceinline__ float cv8(f32x4 v0, f32x4 v1, short8& h, short8& l){
    float ss = 0.f;
#pragma unroll
    for (int j=0;j<4;j++){
        short hb, lb;
        cv2(v0[j], hb, lb); h[j]   = hb; l[j]   = lb;
        cv2(v1[j], hb, lb); h[4+j] = hb; l[4+j] = lb;
        ss += v0[j] + v1[j];
    }
    return ss;
}

// ---- K0: zero G and svec (atomic accumulation targets) ----
__global__ __launch_bounds__(256) void k_zero(float* __restrict__ p){
    const int i = (blockIdx.x*256 + threadIdx.x)*4;
    *(f32x4*)(p + i) = zero4();
}

// ======================= K1: Gram G = sum_n x x^T ==========================
// BEST config (round 19, 168.5 us): 512-thread/8-wave, 32 chunks, GNT=36,
// 4 LDS buffers (64 KB), 2 tiles per barrier, depth-2 register prefetch,
// conflict-free XOR swizzle, 2x4 wave->output mapping (rowgroup pair x
// colgroup half). Round-20's 2-blocks/CU variant regressed (+5.6 us atomic
// tax, no overlap gain) — reverted.
#define GNT 36          // 36 tiles * 32 n = 1152 n per chunk
#define GTS 4096        // shorts per (buf,half): 128*32

__global__ __launch_bounds__(512) void k_gram(const float* __restrict__ x,
                                              float* __restrict__ G,
                                              float* __restrict__ svec){
    __shared__ short Ls[4][2][GTS];    // [buf][hi/lo][row*32 + swizzled col] : 64 KB
    const int b     = blockIdx.y;
    const int chunk = blockIdx.x;      // 32 chunks * 1152 n
    const int tid   = threadIdx.x;
    const int wid   = tid >> 6, lane = tid & 63;
    const int l16   = lane & 15, lgi = lane >> 4;
    const int rgp   = wid >> 1;          // rowgroup pair (rows rgp*32..rgp*32+31)
    const int chh   = wid & 1;           // colgroup half (cg = chh*4..chh*4+3)
    const int sr    = tid >> 2;          // staging row (0..127)
    const int sc8   = (tid & 3) * 8;     // staging col-octet (0,8,16,24)
    const int swzW  = ((sr >> 1) & 3) << 3;
    const int wIdx  = sr*32 + (sc8 ^ swzW);          // staging write index

    const int swzR  = ((l16 >> 1) & 3) << 3;         // read swizzle (row = *16 + l16)
    const int cR    = (lgi*8) ^ swzR;                // swizzled col for b128 reads
    const int raOff0 = (rgp*32      + l16)*32 + cR;  // A-frag idx, rowgroup rgp*2
    const int raOff1 = (rgp*32 + 16 + l16)*32 + cR;  // A-frag idx, rowgroup rgp*2+1

    const float* xs = x + (size_t)b*NC*NHW + (size_t)sr*NHW + chunk*1152 + sc8;

    float srow = 0.f;
    f32x4 acc[2][4];
#pragma unroll
    for (int p=0;p<2;p++)
#pragma unroll
      for (int g=0;g<4;g++) acc[p][g] = zero4();

#define GR_STAGE(BUF, V0, V1)  { short8 h0,l0; srow += cv8(V0,V1,h0,l0); \
        *(short8*)&Ls[BUF][0][wIdx] = h0; *(short8*)&Ls[BUF][1][wIdx] = l0; }

#define GR_COMPUTE(BUF) { \
        const short* Lh = &Ls[BUF][0][0]; \
        const short* Ll = &Ls[BUF][1][0]; \
        short8 hA0 = *(const short8*)(Lh + raOff0); \
        short8 lA0 = *(const short8*)(Ll + raOff0); \
        short8 hA1 = *(const short8*)(Lh + raOff1); \
        short8 lA1 = *(const short8*)(Ll + raOff1); \
        _Pragma("unroll") \
        for (int g=0; g<4; g++){ \
            const int rb = ((chh*4 + g)*16 + l16)*32 + cR; \
            short8 hg  = *(const short8*)(Lh + rb); \
            short8 lg2 = *(const short8*)(Ll + rb); \
            acc[0][g] = __builtin_amdgcn_mfma_f32_16x16x32_bf16(hA0, hg,  acc[0][g], 0,0,0); \
            acc[0][g] = __builtin_amdgcn_mfma_f32_16x16x32_bf16(hA0, lg2, acc[0][g], 0,0,0); \
            acc[0][g] = __builtin_amdgcn_mfma_f32_16x16x32_bf16(lA0, hg,  acc[0][g], 0,0,0); \
            acc[1][g] = __builtin_amdgcn_mfma_f32_16x16x32_bf16(hA1, hg,  acc[1][g], 0,0,0); \
            acc[1][g] = __builtin_amdgcn_mfma_f32_16x16x32_bf16(hA1, lg2, acc[1][g], 0,0,0); \
            acc[1][g] = __builtin_amdgcn_mfma_f32_16x16x32_bf16(lA1, hg,  acc[1][g], 0,0,0); \
        } }

    // prologue: tiles 0,1 staged directly; tiles 2,3 loaded into pair-0 regs
    {
        f32x4 v0 = *(const f32x4*)(xs);
        f32x4 v1 = *(const f32x4*)(xs+4);
        GR_STAGE(0, v0, v1);
        f32x4 u0 = *(const f32x4*)(xs+32);
        f32x4 u1 = *(const f32x4*)(xs+36);
        GR_STAGE(1, u0, u1);
    }
    f32x4 a0A = *(const f32x4*)(xs + 2*32);     // tile 2
    f32x4 a0B = *(const f32x4*)(xs + 2*32 + 4);
    f32x4 b0A = *(const f32x4*)(xs + 3*32);     // tile 3
    f32x4 b0B = *(const f32x4*)(xs + 3*32 + 4);
    f32x4 a1A, a1B, b1A, b1B;
    __syncthreads();

    for (int jp=0; jp<8; ++jp){
        // phase A: compute tiles 4jp,4jp+1 (buf0,1); stage 4jp+2,4jp+3 from
        // pair-0 into buf2,3; load 4jp+4,4jp+5 into pair-1.
        {
            const float* p = xs + (size_t)(4*jp+4)*32;
            a1A = *(const f32x4*)(p);       a1B = *(const f32x4*)(p+4);
            b1A = *(const f32x4*)(p+32);    b1B = *(const f32x4*)(p+36);
        }
        __builtin_amdgcn_sched_barrier(0);
        GR_COMPUTE(0); GR_COMPUTE(1);
        GR_STAGE(2, a0A, a0B); GR_STAGE(3, b0A, b0B);
        __syncthreads();
        // phase B: compute tiles 4jp+2,4jp+3 (buf2,3); stage 4jp+4,4jp+5 from
        // pair-1 into buf0,1; load 4jp+6,4jp+7 into pair-0 (max tile 35 at jp=7).
        {
            const float* p = xs + (size_t)(4*jp+6)*32;
            a0A = *(const f32x4*)(p);       a0B = *(const f32x4*)(p+4);
            b0A = *(const f32x4*)(p+32);    b0B = *(const f32x4*)(p+36);
        }
        __builtin_amdgcn_sched_barrier(0);
        GR_COMPUTE(2); GR_COMPUTE(3);
        GR_STAGE(0, a1A, a1B); GR_STAGE(1, b1A, b1B);
        __syncthreads();
    }
    // after loop: tiles 0..31 computed; tiles 32,33 staged in buf0,1;
    // tiles 34,35 in pair-0 regs (loaded at jp=7 phase B).
    GR_COMPUTE(0); GR_COMPUTE(1);              // tiles 32,33
    GR_STAGE(2, a0A, a0B); GR_STAGE(3, b0A, b0B);   // tiles 34,35
    __syncthreads();
    GR_COMPUTE(2); GR_COMPUTE(3);              // tiles 34,35

#undef GR_STAGE
#undef GR_COMPUTE

    // C/D layout (pass-verified): col = lane&15, row = (lane>>4)*4 + reg
    float* Gb = G + (size_t)b*NC*NC;
#pragma unroll
    for (int p=0;p<2;p++){
        const int rg = rgp*2 + p;
#pragma unroll
        for (int g=0;g<4;g++){
            const int gg = chh*4 + g;
#pragma unroll
            for (int r=0;r<4;r++){
                atomicAdd(&Gb[(size_t)(rg*16 + lgi*4 + r)*NC + gg*16 + l16], acc[p][g][r]);
            }
        }
    }
    srow += __shfl_xor(srow, 1);
    srow += __shfl_xor(srow, 2);
    if ((tid & 3) == 0) atomicAdd(&svec[b*NC + sr], srow);
}

// ---- K2: energy = Wq G Wk^T + rank-1 terms; softmax -> A (LDS); t = A bv; R = A Wv ----
__global__ __launch_bounds__(256) void k_energyav(const float* __restrict__ G,
        const float* __restrict__ svec,
        const float* __restrict__ Wq, const float* __restrict__ bq,
        const float* __restrict__ Wk, const float* __restrict__ bk,
        const float* __restrict__ bv, const float* __restrict__ Wv,
        float* __restrict__ R, float* __restrict__ tvec){
    const int b  = blockIdx.y;
    const int d0 = blockIdx.x * 16;
    const int tid = threadIdx.x;
    const int d  = tid & 15;
    const int ec = tid >> 4;

    __shared__ float Ps[16][128];
    __shared__ float Es[16][128];
    __shared__ float red[16][16];
    __shared__ float rowmax[16];
    __shared__ float rowsum[16];
    __shared__ float qs[16];

    const float* Wqrow = Wq + (size_t)(d0 + d)*NC;
    const float* sb = svec + b*NC;
#pragma unroll
    for (int i=0;i<8;i++){
        const int c = ec*8 + i;
        const float* Grow = G + ((size_t)b*NC + c)*NC;
        float a = 0.f;
        for (int c4=0;c4<32;c4++){
            f32x4 g4 = *(const f32x4*)(Grow + c4*4);
            f32x4 w4 = *(const f32x4*)(Wqrow + c4*4);
            a += g4[0]*w4[0] + g4[1]*w4[1] + g4[2]*w4[2] + g4[3]*w4[3];
        }
        Ps[d][c] = a;
    }
    if (ec == 0){
        float a = 0.f;
        for (int c4=0;c4<32;c4++){
            f32x4 w4 = *(const f32x4*)(Wqrow + c4*4);
            f32x4 s4 = *(const f32x4*)(sb + c4*4);
            a += w4[0]*s4[0] + w4[1]*s4[1] + w4[2]*s4[2] + w4[3]*s4[3];
        }
        qs[d] = a;
    }
    __syncthreads();
    const float bqd = bq[d0+d];
#pragma unroll
    for (int i=0;i<8;i++){
        const int e = ec*8 + i;
        const float* Wkrow = Wk + (size_t)e*NC;
        float ea = 0.f, ks = 0.f;
        for (int c4=0;c4<32;c4++){
            f32x4 w4 = *(const f32x4*)(Wkrow + c4*4);
            f32x4 p4 = *(const f32x4*)(&Ps[d][c4*4]);
            f32x4 s4 = *(const f32x4*)(sb + c4*4);
            ea += w4[0]*p4[0]+w4[1]*p4[1]+w4[2]*p4[2]+w4[3]*p4[3];
            ks += w4[0]*s4[0]+w4[1]*s4[1]+w4[2]*s4[2]+w4[3]*s4[3];
        }
        const float bke = bk[e];
        Es[d][e] = ea + bke*qs[d] + bqd*ks + (float)NHW*bqd*bke;
    }
    float m8 = -3.4e38f;
#pragma unroll
    for (int i=0;i<8;i++) m8 = fmaxf(m8, Es[d][ec*8+i]);
    red[d][ec] = m8;
    __syncthreads();
    if (tid < 16){
        float m = red[tid][0];
        for (int j=1;j<16;j++) m = fmaxf(m, red[tid][j]);
        rowmax[tid] = m;
    }
    __syncthreads();
    const float rm = rowmax[d];
    float s8 = 0.f;
#pragma unroll
    for (int i=0;i<8;i++){
        float ex = expf(Es[d][ec*8+i] - rm);
        Es[d][ec*8+i] = ex;
        s8 += ex;
    }
    red[d][ec] = s8;
    __syncthreads();
    if (tid < 16){
        float sm = 0.f;
        for (int j=0;j<16;j++) sm += red[tid][j];
        rowsum[tid] = sm;
    }
    __syncthreads();
    const float inv = 1.f / rowsum[d];
    float ta = 0.f;
#pragma unroll
    for (int i=0;i<8;i++){
        const int e = ec*8 + i;
        float av = Es[d][e] * inv;
        Es[d][e] = av;
        ta += av * bv[e];
    }
    red[d][ec] = ta;
    __syncthreads();
    if (tid < 16){
        float sm = 0.f;
        for (int j=0;j<16;j++) sm += red[tid][j];
        tvec[b*NC + d0 + tid] = sm;
    }
    const int c0 = ec*8;
    float racc[8];
#pragma unroll
    for (int i=0;i<8;i++) racc[i]=0.f;
    for (int e=0;e<NC;e++){
        const float av = Es[d][e];
        const float* wv = Wv + (size_t)e*NC + c0;
        f32x4 w0 = *(const f32x4*)wv;
        f32x4 w1 = *(const f32x4*)(wv+4);
        racc[0]+=av*w0[0]; racc[1]+=av*w0[1]; racc[2]+=av*w0[2]; racc[3]+=av*w0[3];
        racc[4]+=av*w1[0]; racc[5]+=av*w1[1]; racc[6]+=av*w1[2]; racc[7]+=av*w1[3];
    }
    float* Rrow = R + ((size_t)b*NC + d0 + d)*NC + c0;
#pragma unroll
    for (int i=0;i<8;i++) Rrow[i] = racc[i];
}

// ---- K3: Mb = bf16(I + gamma*Wo*R) single buffer; cvg = gamma*(Wo t + bo) ----
__global__ __launch_bounds__(256) void k_om(const float* __restrict__ R,
        const float* __restrict__ Wo, const float* __restrict__ bo,
        const float* __restrict__ tvec, const float* __restrict__ gamma,
        short* __restrict__ Mb_, float* __restrict__ cvg){
    const int b = blockIdx.y, o0 = blockIdx.x*16;
    const int tid = threadIdx.x, o = tid&15, cc = tid>>4;
    const int c0 = cc*8;                      // cin octet base
    const float* Worow = Wo + (size_t)(o0+o)*NC;
    const float* tb = tvec + b*NC;
    float a[8];
#pragma unroll
    for (int i=0;i<8;i++) a[i]=0.f;
    float cv = 0.f;
    for (int dd=0; dd<NC; dd++){
        const float wv = Worow[dd];
        const float* r = R + ((size_t)b*NC + dd)*NC + c0;
        f32x4 r0 = *(const f32x4*)r;
        f32x4 r1 = *(const f32x4*)(r+4);
        a[0]+=wv*r0[0]; a[1]+=wv*r0[1]; a[2]+=wv*r0[2]; a[3]+=wv*r0[3];
        a[4]+=wv*r1[0]; a[5]+=wv*r1[1]; a[6]+=wv*r1[2]; a[7]+=wv*r1[3];
        cv += wv*tb[dd];
    }
    const float gm = gamma[0];
    const int c   = o0 + o;
    const int cg  = c >> 4;
    const int kst = cc >> 2, lgv = cc & 3;
    const size_t idx = ((((size_t)b*8 + cg)*4 + kst)*64 + (lgv*16 + (c & 15)))*8;
    short8 hh;
#pragma unroll
    for (int i=0;i<8;i++){
        float val = gm*a[i] + ((c0 + i) == c ? 1.f : 0.f);   // M' = I + gm*M
        hh[i] = bfbits(val);
    }
    *(short8*)(Mb_ + idx) = hh;
    if (cc == 0) cvg[b*NC + c] = gm*(cv + bo[c]);
}

// ---- K4: out = M' x + cvg  (A = x from swizzled Xt; B = Mb single bf16) ----
__global__ __launch_bounds__(256, 4) void k_final(const float* __restrict__ x,
        const short* __restrict__ Mb_, const float* __restrict__ cvg,
        float* __restrict__ out){
    __shared__ short Xt[NC*128];   // 32 KB: row n (local), 16 slots of 8 shorts
    const int b   = blockIdx.y;
    const int n0  = blockIdx.x * 128;
    const int tid = threadIdx.x;
    const int wid = tid >> 6, lane = tid & 63;
    const int l16 = lane & 15, lgi = lane >> 4;

    // ---- stage: thread (nr = tid&31, mb8 = tid>>5), 2 reps
    const int nr = tid & 31, mb8 = tid >> 5;
    const float* xs = x + (size_t)b*NC*NHW + n0 + nr*4;
#pragma unroll
    for (int rep=0; rep<2; rep++){
        const int m0 = rep*64 + mb8*8;
        const float* xm = xs + (size_t)m0*NHW;
        f32x4 v0 = *(const f32x4*)(xm);
        f32x4 v1 = *(const f32x4*)(xm + (size_t)1*NHW);
        f32x4 v2 = *(const f32x4*)(xm + (size_t)2*NHW);
        f32x4 v3 = *(const f32x4*)(xm + (size_t)3*NHW);
        f32x4 v4 = *(const f32x4*)(xm + (size_t)4*NHW);
        f32x4 v5 = *(const f32x4*)(xm + (size_t)5*NHW);
        f32x4 v6 = *(const f32x4*)(xm + (size_t)6*NHW);
        f32x4 v7 = *(const f32x4*)(xm + (size_t)7*NHW);
#pragma unroll
        for (int r=0;r<4;r++){
            short8 w;
            w[0]=bfbits(v0[r]); w[1]=bfbits(v1[r]); w[2]=bfbits(v2[r]); w[3]=bfbits(v3[r]);
            w[4]=bfbits(v4[r]); w[5]=bfbits(v5[r]); w[6]=bfbits(v6[r]); w[7]=bfbits(v7[r]);
            const int n = nr*4 + r;
            const int slot = (rep*8 + mb8) ^ ((n>>2)&15) ^ ((n&3)<<2);
            *(short8*)(&Xt[n*128 + slot*8]) = w;
        }
    }
    __syncthreads();

    f32x4 acc[2][8];   // [n 16-block t][cg]
#pragma unroll
    for (int t=0;t<2;t++)
#pragma unroll
      for (int g=0;g<8;g++) acc[t][g]=zero4();

    const short* Mb = Mb_ + (size_t)b*16384;

#pragma unroll
    for (int ks=0; ks<4; ks++){
        const int nA0 = wid*32 + l16;
        const int nA1 = nA0 + 16;
        const int sl  = ks*4 + lgi;
        const int s0  = sl ^ ((nA0>>2)&15) ^ ((nA0&3)<<2);
        const int s1  = sl ^ ((nA1>>2)&15) ^ ((nA1&3)<<2);
        short8 a0 = *(const short8*)(&Xt[nA0*128 + s0*8]);
        short8 a1 = *(const short8*)(&Xt[nA1*128 + s1*8]);
#pragma unroll
        for (int cg=0; cg<8; cg++){
            short8 bh = *(const short8*)(Mb + (((size_t)cg*4 + ks)*64 + lane)*8);
            acc[0][cg] = __builtin_amdgcn_mfma_f32_16x16x32_bf16(a0, bh, acc[0][cg], 0,0,0);
            acc[1][cg] = __builtin_amdgcn_mfma_f32_16x16x32_bf16(a1, bh, acc[1][cg], 0,0,0);
        }
    }

    // C/D: row(i)=n-offset=(lane>>4)*4+r, col(j)=c=cg*16+(lane&15)
    const float* cb = cvg + b*NC;
#pragma unroll
    for (int cg=0;cg<8;cg++){
        const int c = cg*16 + l16;
        const float ccv = cb[c];
        float* orow = &out[((size_t)b*NC + c)*NHW + n0 + wid*32 + lgi*4];
#pragma unroll
        for (int t=0;t<2;t++){
            f32x4 o = acc[t][cg];
            o[0]+=ccv; o[1]+=ccv; o[2]+=ccv; o[3]+=ccv;
            *(f32x4*)(orow + t*16) = o;
        }
    }
}

extern "C" void kernel_launch(void* const* d_in, const int* in_sizes, int n_in,
                              void* d_out, int out_size, void* d_ws, size_t ws_size,
                              hipStream_t stream){
    const float* x     = (const float*)d_in[0];
    const float* Wq    = (const float*)d_in[1];
    const float* bq    = (const float*)d_in[2];
    const float* Wk    = (const float*)d_in[3];
    const float* bk    = (const float*)d_in[4];
    const float* Wv    = (const float*)d_in[5];
    const float* bv    = (const float*)d_in[6];
    const float* Wo    = (const float*)d_in[7];
    const float* bo    = (const float*)d_in[8];
    const float* gamma = (const float*)d_in[9];
    float* out = (float*)d_out;

    float* w  = (float*)d_ws;
    float* G  = w + GOFF;
    float* S  = w + SOFF;
    float* T  = w + TOFF;
    float* R  = w + ROFF;
    float* CV = w + CVOFF;
    short* Mb = (short*)(w + MBOFF);

    // zero atomic-accumulation targets (G: 131072 + svec: 1024 floats)
    k_zero    <<<dim3(129),     256, 0, stream>>>(G);

    k_gram    <<<dim3(32,  NB), 512, 0, stream>>>(x, G, S);
    k_energyav<<<dim3(8,   NB), 256, 0, stream>>>(G, S, Wq, bq, Wk, bk, bv, Wv, R, T);
    k_om      <<<dim3(8,   NB), 256, 0, stream>>>(R, Wo, bo, T, gamma, Mb, CV);
    k_final   <<<dim3(288, NB), 256, 0, stream>>>(x, Mb, CV, out);
}